// Round 1
// baseline (565.721 us; speedup 1.0000x reference)
//
#include <hip/hip_runtime.h>

#define L_TOT   4096
#define BATCH   16
#define CIN     32
#define IN_FEAT 288        // 32 * 3 * 3
#define OUT_CH  64
#define G_L     4          // locations per block
#define P_STR   292        // patch row stride (pad 288 -> 292: bank-offset 4 per b, b128-conflict-free)

__global__ __launch_bounds__(256, 4)
void lc2d_kernel(const float* __restrict__ x,
                 const float* __restrict__ weight,
                 const float* __restrict__ bias,
                 float* __restrict__ out) {
    __shared__ float patch[BATCH][P_STR];      // 18.7 KB

    const int tid = threadIdx.x;
    const int b   = tid >> 4;                  // 0..15
    const int o4  = tid & 15;                  // 0..15 -> o = 4*o4..4*o4+3
    const int l0  = blockIdx.x * G_L;          // 4 consecutive l, same output row (64 % 4 == 0)

    const float4* __restrict__ W4 = (const float4*)weight;  // [l][i][o4] of float4
    const float4* __restrict__ B4 = (const float4*)bias;    // [l][o4]

    float4 acc[G_L];

#pragma unroll
    for (int g = 0; g < G_L; ++g) {
        const int l  = l0 + g;
        const int oh = l >> 6;
        const int ow = l & 63;

        // ---- cooperative fill of patch[b][i] for this l (4608 elems, 18/thread) ----
        for (int e = tid; e < BATCH * IN_FEAT; e += 256) {
            int bb = e / IN_FEAT;
            int i  = e - bb * IN_FEAT;         // i = c*9 + ki*3 + kj (torch unfold order)
            int c  = i / 9;
            int r  = i - c * 9;
            int ki = r / 3;
            int kj = r - ki * 3;
            int h  = oh - 1 + ki;
            int w  = ow - 1 + kj;
            float v = 0.0f;
            if ((unsigned)h < 64u && (unsigned)w < 64u)
                v = x[((bb * CIN + c) * 64 + h) * 64 + w];
            patch[bb][i] = v;
        }
        __syncthreads();

        // ---- compute: acc = bias + patches(b,:) * W(l,:,o) ----
        float4 a = B4[l * 16 + o4];
        const float4* __restrict__ Wl = W4 + (size_t)l * IN_FEAT * 16 + o4;
        const float*  __restrict__ pb = patch[b];
        for (int i0 = 0; i0 < IN_FEAT; i0 += 4) {
            float4 p  = *(const float4*)(pb + i0);   // ds_read_b128, bank-conflict-free
            float4 w0 = Wl[(i0 + 0) * 16];
            float4 w1 = Wl[(i0 + 1) * 16];
            float4 w2 = Wl[(i0 + 2) * 16];
            float4 w3 = Wl[(i0 + 3) * 16];
            a.x += p.x * w0.x; a.y += p.x * w0.y; a.z += p.x * w0.z; a.w += p.x * w0.w;
            a.x += p.y * w1.x; a.y += p.y * w1.y; a.z += p.y * w1.z; a.w += p.y * w1.w;
            a.x += p.z * w2.x; a.y += p.z * w2.y; a.z += p.z * w2.z; a.w += p.z * w2.w;
            a.x += p.w * w3.x; a.y += p.w * w3.y; a.z += p.w * w3.z; a.w += p.w * w3.w;
        }
        acc[g] = a;
        __syncthreads();   // protect patch before next g's fill
    }

    // ---- store: float4 over the 4 l's for each of this thread's 4 o values ----
    // out flat index: ((b*64 + o) * 4096 + l)
    const int ob = b * OUT_CH + o4 * 4;
    *(float4*)(out + (size_t)(ob + 0) * L_TOT + l0) =
        make_float4(acc[0].x, acc[1].x, acc[2].x, acc[3].x);
    *(float4*)(out + (size_t)(ob + 1) * L_TOT + l0) =
        make_float4(acc[0].y, acc[1].y, acc[2].y, acc[3].y);
    *(float4*)(out + (size_t)(ob + 2) * L_TOT + l0) =
        make_float4(acc[0].z, acc[1].z, acc[2].z, acc[3].z);
    *(float4*)(out + (size_t)(ob + 3) * L_TOT + l0) =
        make_float4(acc[0].w, acc[1].w, acc[2].w, acc[3].w);
}

extern "C" void kernel_launch(void* const* d_in, const int* in_sizes, int n_in,
                              void* d_out, int out_size, void* d_ws, size_t ws_size,
                              hipStream_t stream) {
    const float* x      = (const float*)d_in[0];
    const float* weight = (const float*)d_in[1];
    const float* bias   = (const float*)d_in[2];
    float* out          = (float*)d_out;

    dim3 grid(L_TOT / G_L);   // 1024 blocks
    dim3 block(256);
    hipLaunchKernelGGL(lc2d_kernel, grid, block, 0, stream, x, weight, bias, out);
}

// Round 2
// 488.969 us; speedup vs baseline: 1.1570x; 1.1570x over previous
//
#include <hip/hip_runtime.h>

#define L_TOT   4096
#define BATCH   16
#define CIN     32
#define IN_FEAT 288        // 32 * 3 * 3
#define OUT_CH  64
#define G_L     4          // locations per block (same output row)
#define NROW    576        // 32c * 3dh * 6wl rows in the x tile
#define NB      18         // batches of 4 i-steps (72 steps/lane, i = 4*st + q)

// p fragment address: xs row for feature i=(c,ki,kj) at location offset g
__device__ __forceinline__ const float4* p_addr(const float* pb_base, int q, int g, int st) {
    int i   = (st << 2) + q;        // this lane's feature index
    int c   = i / 9;
    int r   = i - 9 * c;
    int ki  = r / 3;
    int kj  = r - 3 * ki;
    int row = (c * 3 + ki) * 6 + g + kj;
    return (const float4*)(pb_base + (row << 4));
}

#define FMA_BATCH(CUR)                                                                  \
    _Pragma("unroll")                                                                   \
    for (int u = 0; u < 4; ++u) {                                                       \
        const float4 wv4 = wbuf[CUR][u];                                                \
        const float4 pv  = pbuf[CUR][u];                                                \
        acc[0][0] += pv.x * wv4.x; acc[0][1] += pv.x * wv4.y;                           \
        acc[0][2] += pv.x * wv4.z; acc[0][3] += pv.x * wv4.w;                           \
        acc[1][0] += pv.y * wv4.x; acc[1][1] += pv.y * wv4.y;                           \
        acc[1][2] += pv.y * wv4.z; acc[1][3] += pv.y * wv4.w;                           \
        acc[2][0] += pv.z * wv4.x; acc[2][1] += pv.z * wv4.y;                           \
        acc[2][2] += pv.z * wv4.z; acc[2][3] += pv.z * wv4.w;                           \
        acc[3][0] += pv.w * wv4.x; acc[3][1] += pv.w * wv4.y;                           \
        acc[3][2] += pv.w * wv4.z; acc[3][3] += pv.w * wv4.w;                           \
    }

__global__ __launch_bounds__(256, 4)
void lc2d_v2(const float* __restrict__ x,
             const float* __restrict__ weight,
             const float* __restrict__ bias,
             float* __restrict__ out) {
    __shared__ float xs[NROW * 16];   // [row][b], 36.9 KB -> 4 blocks/CU

    const int tid  = threadIdx.x;
    const int lane = tid & 63;
    const int wv   = tid >> 6;        // wave id -> b-quad base 4*wv
    const int o4   = lane & 15;       // o-quad index (o = 4*o4 .. 4*o4+3)
    const int q    = lane >> 4;       // i-phase 0..3
    const int l0   = blockIdx.x * G_L;
    const int oh   = l0 >> 6;
    const int ow0  = l0 & 63;

    // ---- stage x tile ONCE: xs[row][b], row = (c*3+dh)*6 + wl ----
    for (int e = tid; e < NROW * 16; e += 256) {
        int b   = e & 15;
        int row = e >> 4;
        int wl  = row % 6;
        int t   = row / 6;
        int dh  = t % 3;
        int c   = t / 3;
        int h   = oh - 1 + dh;
        int w   = ow0 - 1 + wl;
        float v = 0.0f;
        if ((unsigned)h < 64u && (unsigned)w < 64u)
            v = x[((b * CIN + c) * 64 + h) * 64 + w];
        xs[row * 16 + b] = v;
    }
    __syncthreads();   // the ONLY barrier

    const float4* __restrict__ W4 = (const float4*)weight;
    const float4* __restrict__ B4 = (const float4*)bias;
    const float*  pb_base = xs + (wv << 2);   // this wave's b-quad column

    float res[G_L][4];

    for (int g = 0; g < G_L; ++g) {
        const int l = l0 + g;
        float acc[4][4] = {{0.0f, 0.0f, 0.0f, 0.0f},
                           {0.0f, 0.0f, 0.0f, 0.0f},
                           {0.0f, 0.0f, 0.0f, 0.0f},
                           {0.0f, 0.0f, 0.0f, 0.0f}};

        // lane's weight stream: contiguous 1024 B per wave-instruction
        const float4* wp = W4 + (size_t)l * (IN_FEAT * 16) + (q << 4) + o4;

        float4 wbuf[2][4], pbuf[2][4];

        // prologue: batch 0 (steps 0..3)
#pragma unroll
        for (int u = 0; u < 4; ++u) {
            wbuf[0][u] = wp[u << 6];
            pbuf[0][u] = *p_addr(pb_base, q, g, u);
        }

#pragma unroll 2
        for (int sb = 0; sb < NB - 1; ++sb) {
            const int cur = sb & 1, nxt = cur ^ 1;
            const int st0 = (sb + 1) << 2;
            // prefetch next batch (4 global float4 + 4 ds_read_b128 in flight)
#pragma unroll
            for (int u = 0; u < 4; ++u) {
                wbuf[nxt][u] = wp[(size_t)(st0 + u) << 6];
                pbuf[nxt][u] = *p_addr(pb_base, q, g, st0 + u);
            }
            FMA_BATCH(cur)
        }
        FMA_BATCH((NB - 1) & 1)   // epilogue: last batch (17 & 1 == 1)

        // in-wave reduction over the 4 i-phases (lanes 16/32 apart)
#pragma unroll
        for (int bq = 0; bq < 4; ++bq) {
#pragma unroll
            for (int j = 0; j < 4; ++j) {
                float v = acc[bq][j];
                v += __shfl_xor(v, 16);
                v += __shfl_xor(v, 32);
                acc[bq][j] = v;
            }
        }

        const float4 bias4 = B4[l * 16 + o4];
        float rj[4];
#pragma unroll
        for (int j = 0; j < 4; ++j) {
            float v = acc[0][j];
            v = (q == 1) ? acc[1][j] : v;
            v = (q == 2) ? acc[2][j] : v;
            v = (q == 3) ? acc[3][j] : v;
            rj[j] = v;
        }
        res[g][0] = rj[0] + bias4.x;
        res[g][1] = rj[1] + bias4.y;
        res[g][2] = rj[2] + bias4.z;
        res[g][3] = rj[3] + bias4.w;
    }

    // stores: float4 over l for each of this lane's 4 o values, b = 4*wv + q
    const int b_out = (wv << 2) + q;
    float* op = out + ((size_t)(b_out * OUT_CH) + (o4 << 2)) * L_TOT + l0;
#pragma unroll
    for (int j = 0; j < 4; ++j) {
        *(float4*)(op + (size_t)j * L_TOT) =
            make_float4(res[0][j], res[1][j], res[2][j], res[3][j]);
    }
}

extern "C" void kernel_launch(void* const* d_in, const int* in_sizes, int n_in,
                              void* d_out, int out_size, void* d_ws, size_t ws_size,
                              hipStream_t stream) {
    const float* x      = (const float*)d_in[0];
    const float* weight = (const float*)d_in[1];
    const float* bias   = (const float*)d_in[2];
    float* out          = (float*)d_out;

    dim3 grid(L_TOT / G_L);   // 1024 blocks = 4 blocks/CU
    dim3 block(256);
    hipLaunchKernelGGL(lc2d_v2, grid, block, 0, stream, x, weight, bias, out);
}

// Round 4
// 457.664 us; speedup vs baseline: 1.2361x; 1.0684x over previous
//
#include <hip/hip_runtime.h>

#define L_TOT   4096
#define CIN     32
#define G_L     4          // locations per block (same output row)
#define NROW    576        // rows: (c*3+dh)*6 + wl
#define NSTAGE  96         // s = c*3 + ki ; feature i = 3s + kj

// 16 FMAs: acc[bq][j] += PP.bq * WW.j   (params MUST NOT be named x/y/z/w/p/w!)
#define FMA16(PP, WW) {                                                        \
    acc[0][0] += PP.x * WW.x; acc[0][1] += PP.x * WW.y;                        \
    acc[0][2] += PP.x * WW.z; acc[0][3] += PP.x * WW.w;                        \
    acc[1][0] += PP.y * WW.x; acc[1][1] += PP.y * WW.y;                        \
    acc[1][2] += PP.y * WW.z; acc[1][3] += PP.y * WW.w;                        \
    acc[2][0] += PP.z * WW.x; acc[2][1] += PP.z * WW.y;                        \
    acc[2][2] += PP.z * WW.z; acc[2][3] += PP.z * WW.w;                        \
    acc[3][0] += PP.w * WW.x; acc[3][1] += PP.w * WW.y;                        \
    acc[3][2] += PP.w * WW.z; acc[3][3] += PP.w * WW.w; }

// prefetch stage SS weight rows (3 x float4, contiguous 1024 B per wave-instr)
#define WLOAD(BB, SS) {                                                        \
    BB[0] = wp[(3 * (SS) + 0) * 16];                                           \
    BB[1] = wp[(3 * (SS) + 1) * 16];                                           \
    BB[2] = wp[(3 * (SS) + 2) * 16]; }

// compute stage SS against buffer BB (3 LDS b128 reads + 48 FMA)
#define STEP(BB, SS) {                                                         \
    const float* pr = xs + ((6 * (SS) + g) << 4) + (wv << 2);                  \
    float4 p0 = *(const float4*)(pr);                                          \
    float4 p1 = *(const float4*)(pr + 16);                                     \
    float4 p2 = *(const float4*)(pr + 32);                                     \
    FMA16(p0, BB[0]); FMA16(p1, BB[1]); FMA16(p2, BB[2]); }

__global__ __launch_bounds__(256, 4)
void lc2d_v3(const float* __restrict__ x,
             const float* __restrict__ weight,
             const float* __restrict__ bias,
             float* __restrict__ out) {
    __shared__ float xs[NROW * 16];   // [row][b], 36864 B -> 4 blocks/CU

    const int tid  = threadIdx.x;
    const int lane = tid & 63;
    const int wv   = tid >> 6;        // wave id -> b-quad base 4*wv
    const int g    = lane >> 4;       // location offset 0..3
    const int o4   = lane & 15;       // o-quad (o = 4*o4 .. 4*o4+3)
    const int l0   = blockIdx.x * G_L;
    const int oh   = l0 >> 6;
    const int ow0  = l0 & 63;

    // ---- stage x tile ONCE: xs[(t*6+wl)*16 + b] = x[b, c, oh-1+dh, ow0-1+wl]
    for (int u = tid; u < 1536; u += 256) {       // u = (c*3+dh)*16 + b
        int b  = u & 15;
        int t  = u >> 4;           // c*3 + dh
        int dh = t % 3;
        int c  = t / 3;
        int h  = oh - 1 + dh;
        bool hok = (unsigned)h < 64u;
        const float* xrow = x + (((b * CIN + c) * 64 + h) << 6);
        int wbase = ow0 - 1;
#pragma unroll
        for (int wl = 0; wl < 6; ++wl) {
            int ww = wbase + wl;
            float v = (hok && (unsigned)ww < 64u) ? xrow[ww] : 0.0f;
            xs[(t * 6 + wl) * 16 + b] = v;
        }
    }
    __syncthreads();   // the only barrier

    const float4* __restrict__ W4 = (const float4*)weight;
    // lane weight stream: W[l0+g][i][o-quad o4]
    const float4* wp = W4 + (size_t)(l0 + g) * (288 * 16) + o4;

    const float4 bias4 = ((const float4*)bias)[(l0 + g) * 16 + o4];
    float acc[4][4];
#pragma unroll
    for (int bq = 0; bq < 4; ++bq) {
        acc[bq][0] = bias4.x; acc[bq][1] = bias4.y;
        acc[bq][2] = bias4.z; acc[bq][3] = bias4.w;
    }

    // ---- main loop: 96 stages, 4-deep rotating prefetch, all-static indices
    float4 bA[3], bB[3], bC[3], bD[3];   // buffer for stage s is [A,B,C,D][s & 3]
    WLOAD(bA, 0); WLOAD(bB, 1); WLOAD(bC, 2);

    for (int t = 0; t < 23; ++t) {
        const int s = t * 4;
        WLOAD(bD, s + 3); STEP(bA, s);
        WLOAD(bA, s + 4); STEP(bB, s + 1);
        WLOAD(bB, s + 5); STEP(bC, s + 2);
        WLOAD(bC, s + 6); STEP(bD, s + 3);
    }
    // loaded 0..94, computed 0..91
    WLOAD(bD, 95); STEP(bA, 92);
    STEP(bB, 93); STEP(bC, 94); STEP(bD, 95);

    // ---- stores: out[(b*64 + o)*4096 + l0 + g], b = 4*wv+bq, o = 4*o4+j
#pragma unroll
    for (int bq = 0; bq < 4; ++bq) {
        const int b = (wv << 2) + bq;
#pragma unroll
        for (int j = 0; j < 4; ++j) {
            out[((size_t)((b << 6) + (o4 << 2) + j) << 12) + l0 + g] = acc[bq][j];
        }
    }
}

extern "C" void kernel_launch(void* const* d_in, const int* in_sizes, int n_in,
                              void* d_out, int out_size, void* d_ws, size_t ws_size,
                              hipStream_t stream) {
    const float* x      = (const float*)d_in[0];
    const float* weight = (const float*)d_in[1];
    const float* bias   = (const float*)d_in[2];
    float* out          = (float*)d_out;

    dim3 grid(L_TOT / G_L);   // 1024 blocks = 4 blocks/CU
    dim3 block(256);
    hipLaunchKernelGGL(lc2d_v3, grid, block, 0, stream, x, weight, bias, out);
}

// Round 6
// 444.345 us; speedup vs baseline: 1.2732x; 1.0300x over previous
//
#include <hip/hip_runtime.h>

#define L_TOT   4096
#define CIN     32
#define G_L     4            // locations per block (same output row)
#define CH      4            // stages per chunk (stage s = c*3+ki, feature i = 3s+kj)
#define NCHUNK  24           // 96 stages total
#define CHUNK_STRIDE_F (CH * 3 * 64)   // 768 floats = 3072 B per location per chunk
// LDS: xs 36864 B + wsm 2*12288 B = 61440 B -> 2 blocks/CU

using f32g = __attribute__((address_space(1))) const float;
using f32l = __attribute__((address_space(3))) float;

// 16 FMAs: acc[bq][j] += PP.bq * WW.j  (param names must avoid x/y/z/w)
#define FMA16(PP, WW) {                                                        \
    acc[0][0] += PP.x * WW.x; acc[0][1] += PP.x * WW.y;                        \
    acc[0][2] += PP.x * WW.z; acc[0][3] += PP.x * WW.w;                        \
    acc[1][0] += PP.y * WW.x; acc[1][1] += PP.y * WW.y;                        \
    acc[1][2] += PP.y * WW.z; acc[1][3] += PP.y * WW.w;                        \
    acc[2][0] += PP.z * WW.x; acc[2][1] += PP.z * WW.y;                        \
    acc[2][2] += PP.z * WW.z; acc[2][3] += PP.z * WW.w;                        \
    acc[3][0] += PP.w * WW.x; acc[3][1] += PP.w * WW.y;                        \
    acc[3][2] += PP.w * WW.z; acc[3][3] += PP.w * WW.w; }

__global__ __launch_bounds__(256, 2)
void lc2d_v6(const float* __restrict__ x,
             const float* __restrict__ weight,
             const float* __restrict__ bias,
             float* __restrict__ out) {
    __shared__ __align__(16) float xs[576 * 16];     // [row=(c*3+dh)*6+wl][b]
    __shared__ __align__(16) float wsm[2][12 * 256]; // [buf][3072 floats = 12 KB]

    const int tid  = threadIdx.x;
    const int lane = tid & 63;
    const int wv   = tid >> 6;        // wave id -> b-quad base 4*wv
    const int g    = lane >> 4;       // location offset 0..3
    const int o4   = lane & 15;       // o-quad (o = 4*o4 .. 4*o4+3)
    const int l0   = blockIdx.x * G_L;
    const int oh   = l0 >> 6;
    const int ow0  = l0 & 63;

    // ---- per-wave DMA piece setup: pieces p = wv, wv+4, wv+8 of each 12 KB chunk
    // piece p covers bytes [p*1024, p*1024+1024) of the chunk;
    // chunk layout = 4 l-slabs of 3072 B (l = l0+gg, gg = p/3), i-major within slab.
    const float* gsrc[3];
    int ldsoff[3];
#pragma unroll
    for (int t = 0; t < 3; ++t) {
        int p   = wv + (t << 2);      // 0..11, wave-uniform
        int gg  = p / 3;
        int sub = p - 3 * gg;
        gsrc[t] = weight + (size_t)(l0 + gg) * (288 * 64) + sub * 256 + (lane << 2);
        ldsoff[t] = p * 256;          // float offset of piece base in wsm[buf]
    }

    // ---- prologue: DMA chunk 0 while filling the x tile ----
#pragma unroll
    for (int t = 0; t < 3; ++t)
        __builtin_amdgcn_global_load_lds((f32g*)(gsrc[t]),
                                         (f32l*)(&wsm[0][ldsoff[t]]), 16, 0, 0);

    for (int u = tid; u < 1536; u += 256) {       // u = (c*3+dh)*16 + b
        int b  = u & 15;
        int t  = u >> 4;              // c*3 + dh
        int dh = t % 3;
        int c  = t / 3;
        int h  = oh - 1 + dh;
        bool hok = (unsigned)h < 64u;
        const float* xrow = x + (((b * CIN + c) * 64 + h) << 6);
        int wbase = ow0 - 1;
#pragma unroll
        for (int wl = 0; wl < 6; ++wl) {
            int ww = wbase + wl;
            float v = (hok && (unsigned)ww < 64u) ? xrow[ww] : 0.0f;
            xs[(t * 6 + wl) * 16 + b] = v;
        }
    }
    __syncthreads();   // drains DMA(0) + x fill for everyone

    const float4 bias4 = ((const float4*)bias)[(l0 + g) * 16 + o4];
    float acc[4][4];
#pragma unroll
    for (int bq = 0; bq < 4; ++bq) {
        acc[bq][0] = bias4.x; acc[bq][1] = bias4.y;
        acc[bq][2] = bias4.z; acc[bq][3] = bias4.w;
    }

    // ---- main pipeline: issue DMA(k+1) into nxt, compute(k) from cur, barrier
    int buf = 0;
    for (int k = 0; k < NCHUNK - 1; ++k) {
#pragma unroll
        for (int t = 0; t < 3; ++t)
            __builtin_amdgcn_global_load_lds((f32g*)(gsrc[t] + (size_t)(k + 1) * CHUNK_STRIDE_F),
                                             (f32l*)(&wsm[buf ^ 1][ldsoff[t]]), 16, 0, 0);
#pragma unroll
        for (int sl = 0; sl < CH; ++sl) {
            const int s = (k << 2) + sl;
            const float* pr = xs + ((6 * s + g) << 4) + (wv << 2);
            float4 p0 = *(const float4*)(pr);
            float4 p1 = *(const float4*)(pr + 16);
            float4 p2 = *(const float4*)(pr + 32);
            const float4* wr = (const float4*)&wsm[buf][0] + g * 192 + sl * 48 + o4;
            float4 w0 = wr[0];
            float4 w1 = wr[16];
            float4 w2 = wr[32];
            FMA16(p0, w0); FMA16(p1, w1); FMA16(p2, w2);
        }
        __syncthreads();   // vmcnt(0) drain: DMA(k+1) had full compute(k) to fly
        buf ^= 1;
    }
    // final chunk (k = 23), already resident in wsm[buf]
#pragma unroll
    for (int sl = 0; sl < CH; ++sl) {
        const int s = ((NCHUNK - 1) << 2) + sl;
        const float* pr = xs + ((6 * s + g) << 4) + (wv << 2);
        float4 p0 = *(const float4*)(pr);
        float4 p1 = *(const float4*)(pr + 16);
        float4 p2 = *(const float4*)(pr + 32);
        const float4* wr = (const float4*)&wsm[buf][0] + g * 192 + sl * 48 + o4;
        float4 w0 = wr[0];
        float4 w1 = wr[16];
        float4 w2 = wr[32];
        FMA16(p0, w0); FMA16(p1, w1); FMA16(p2, w2);
    }

    // ---- stores: out[((b*64 + o) << 12) + l0 + g], b = 4*wv+bq, o = 4*o4+j
#pragma unroll
    for (int bq = 0; bq < 4; ++bq) {
        const int b = (wv << 2) + bq;
#pragma unroll
        for (int j = 0; j < 4; ++j) {
            out[((size_t)((b << 6) + (o4 << 2) + j) << 12) + l0 + g] = acc[bq][j];
        }
    }
}

extern "C" void kernel_launch(void* const* d_in, const int* in_sizes, int n_in,
                              void* d_out, int out_size, void* d_ws, size_t ws_size,
                              hipStream_t stream) {
    const float* x      = (const float*)d_in[0];
    const float* weight = (const float*)d_in[1];
    const float* bias   = (const float*)d_in[2];
    float* out          = (float*)d_out;

    dim3 grid(L_TOT / G_L);   // 1024 blocks = 2 resident/CU, 4 total/CU
    dim3 block(256);
    hipLaunchKernelGGL(lc2d_v6, grid, block, 0, stream, x, weight, bias, out);
}